// Round 1
// baseline (19457.074 us; speedup 1.0000x reference)
//
#include <hip/hip_runtime.h>

// Problem constants
#define Bx    256
#define Tx    512
#define LAT   128
#define CND   32
#define HIDN  512
#define OUTD  64
#define KD    608           // K = 64(prev) + 32(cond) + 512(h)
#define KP    616           // padded LDS/Wg stride in bf16 elems
#define ROWS  32            // batch rows per block
#define NCOLS 32            // gate cols per block (8 units x 4 gates)

typedef unsigned short u16;
typedef unsigned int   u32;
typedef short s16x8 __attribute__((ext_vector_type(8)));
typedef unsigned short u16x8 __attribute__((ext_vector_type(8)));
typedef unsigned short u16x4 __attribute__((ext_vector_type(4)));
typedef float f32x4 __attribute__((ext_vector_type(4)));

// ws layout (bytes)
#define WG_SLICE (NCOLS * KP * 2)            // 39424 B per hidden slice
#define WG_OFF   0
#define WG_BYTES (64 * WG_SLICE)             // 2523136
#define H0_OFF   (WG_BYTES)                  // h double-buffer, bf16 bits
#define H1_OFF   (H0_OFF + Bx * HIDN * 2)
#define CB_OFF   (H1_OFF + Bx * HIDN * 2)    // c0, fp32 (read once by persist)
#define BS_OFF   (CB_OFF + Bx * HIDN * 4)    // b_ih+b_hh, fp32 [2048]
#define DN_OFF   (BS_OFF + 4 * HIDN * 4)     // done counters u32[512*8]

// persistent-kernel LDS layout
#define A_BYTES  (ROWS * KP * 2)             // 39424
#define SMEM_SZ  (2 * A_BYTES + HIDN * 4)    // 80896 -> 2 blocks/CU
#define WCHUNK   (A_BYTES / 16)              // 2464 16B chunks per W slice

__device__ __forceinline__ float sigmoidf_(float x) { return 1.0f / (1.0f + __expf(-x)); }

__device__ __forceinline__ u16 f2bf(float f) {          // RNE fp32 -> bf16 bits
    union { float f; u32 u; } v; v.f = f;
    u32 r = (v.u + 0x7FFFu + ((v.u >> 16) & 1u)) >> 16;
    return (u16)r;
}
__device__ __forceinline__ float bf2f(u16 s) {
    union { u32 u; float f; } v; v.u = ((u32)s) << 16;
    return v.f;
}
__device__ __forceinline__ void gl_lds16(const void* g, void* l) {
    __builtin_amdgcn_global_load_lds(
        (const __attribute__((address_space(1))) unsigned int*)g,
        (__attribute__((address_space(3))) unsigned int*)l, 16, 0, 0);
}

// ---------------------------------------------------------------------------
// prep: gather [W_ih | W_hh] -> bf16 Wg[hs][col=g*8+u][k(pad 616)]; bsum; zero done
// ---------------------------------------------------------------------------
__global__ __launch_bounds__(256) void prep_w(
    const float* __restrict__ W_ih, const float* __restrict__ W_hh,
    const float* __restrict__ b_ih, const float* __restrict__ b_hh,
    u16* __restrict__ Wg, float* __restrict__ bsum, u32* __restrict__ done_arr)
{
    const int idx = blockIdx.x * 256 + threadIdx.x;
    if (idx < 64 * NCOLS * KD) {
        const int k   = idx % KD;
        const int t   = idx / KD;
        const int col = t % NCOLS;
        const int hs  = t / NCOLS;
        const int g = col >> 3, u = col & 7;
        const int n = g * HIDN + hs * 8 + u;
        const float v = (k < 96) ? W_ih[n * 96 + k] : W_hh[n * HIDN + (k - 96)];
        Wg[(hs * NCOLS + col) * KP + k] = f2bf(v);
    }
    if (idx < 4 * HIDN) bsum[idx] = b_ih[idx] + b_hh[idx];
    if (idx < Tx * 8)   done_arr[idx] = 0u;
}

// ---------------------------------------------------------------------------
// init: h0 (bf16) = latent @ W_lh^T + b_lh ; c0 (fp32) ; out[:,0,:] = 1
// ---------------------------------------------------------------------------
__global__ __launch_bounds__(256) void init_kernel(
    const float* __restrict__ latent, const float* __restrict__ W_lh,
    const float* __restrict__ b_lh,   const float* __restrict__ W_lc,
    const float* __restrict__ b_lc,   u16* __restrict__ h0,
    float* __restrict__ c0,           float* __restrict__ out)
{
    const int b = blockIdx.x;
    const float4* lat4 = reinterpret_cast<const float4*>(latent + b * LAT);
#pragma unroll
    for (int jj = 0; jj < 2; ++jj) {
        const int j = threadIdx.x + jj * 256;
        const float4* wh4 = reinterpret_cast<const float4*>(W_lh + j * LAT);
        const float4* wc4 = reinterpret_cast<const float4*>(W_lc + j * LAT);
        float sh = 0.f, sc = 0.f;
#pragma unroll 8
        for (int k = 0; k < LAT / 4; ++k) {
            float4 l = lat4[k], a = wh4[k], c = wc4[k];
            sh += l.x * a.x + l.y * a.y + l.z * a.z + l.w * a.w;
            sc += l.x * c.x + l.y * c.y + l.z * c.z + l.w * c.w;
        }
        h0[b * HIDN + j] = f2bf(sh + b_lh[j]);
        c0[b * HIDN + j] = sc + b_lc[j];
    }
    if (threadIdx.x < OUTD) out[b * (Tx * OUTD) + threadIdx.x] = 1.0f;
}

// ---------------------------------------------------------------------------
// persistent kernel: all 512 steps in one cooperative launch.
// grid 512 = 8 batch groups (bs = blockIdx&7, XCD-local heuristic) x 64 hidden
// slices. Weights stay in LDS; c state stays in registers; per-step sync is a
// 64-block group counter (device-scope atomics + agent fences, mapping-safe).
// ---------------------------------------------------------------------------
__global__ __launch_bounds__(256, 2) void persist_kernel(
    const float* __restrict__ target, const float* __restrict__ cond,
    u16* __restrict__ hbuf0, u16* __restrict__ hbuf1,
    const float* __restrict__ cbuf, const u16* __restrict__ Wg,
    const float* __restrict__ bsum, const float* __restrict__ W_out,
    const float* __restrict__ b_out, float* __restrict__ out,
    u32* __restrict__ done)
{
    const int tid  = threadIdx.x;
    const int bs   = blockIdx.x & 7;    // group = batch slice (same XCD under %8 map)
    const int hs   = blockIdx.x >> 3;   // hidden slice 0..63
    const int w    = tid >> 6;
    const int lane = tid & 63;

    __shared__ __align__(16) char smem[SMEM_SZ];
    u16*   As   = (u16*)smem;                   // [32][616] activations
    u16*   Ws   = (u16*)(smem + A_BYTES);       // [32][616] weights (persistent)
    float* Wo   = (float*)(smem + 2 * A_BYTES); // [512] W_out col (persistent)
    float* gbuf = (float*)smem;                 // [32][36] alias over As rows 0-3

    // ---- one-time: W slice -> LDS (2464 x 16B chunks, exact, no tail pad)
    {
        const u16* wsrc = Wg + hs * (NCOLS * KP);
#pragma unroll
        for (int it = 0; it < 10; ++it) {
            const int base = it * 256 + w * 64;
            if (base + lane < WCHUNK)
                gl_lds16(wsrc + (base + lane) * 8, (void*)(Ws + base * 8));
        }
    }
    if (tid < 128)
        reinterpret_cast<float4*>(Wo)[tid] =
            reinterpret_cast<const float4*>(W_out + hs * HIDN)[tid];

    const int r_  = tid >> 3, q_ = tid & 7;     // (row, unit) ownership
    const int gb_ = bs * ROWS + r_;
    const int hu_ = hs * 8 + q_;
    float c_reg = cbuf[gb_ * HIDN + hu_];       // c lives in a register forever
    const float bsum0 = bsum[0 * HIDN + hu_];
    const float bsum1 = bsum[1 * HIDN + hu_];
    const float bsum2 = bsum[2 * HIDN + hu_];
    const float bsum3 = bsum[3 * HIDN + hu_];
    const float bo    = b_out[hs];

    u16x4 cond_bf;                              // cond cached in regs (re-written each
    {                                           // step since gbuf aliases As rows 0-3)
        const float4 cv = *reinterpret_cast<const float4*>(cond + gb_ * CND + q_ * 4);
        cond_bf[0] = f2bf(cv.x); cond_bf[1] = f2bf(cv.y);
        cond_bf[2] = f2bf(cv.z); cond_bf[3] = f2bf(cv.w);
    }

    // MFMA geometry (verified layout from step_kernel)
    const int mrow = ((w & 1) << 4) + (lane & 15);
    const int ncol = ((w >> 1) << 4) + (lane & 15);
    const int kq   = (lane >> 4) << 3;
    const u16* ap  = As + mrow * KP + kq;
    const u16* bp  = Ws + ncol * KP + kq;
    const int row0 = ((w & 1) << 4) + ((lane >> 4) << 2);

    for (int j = 0; j < Tx; ++j) {
        // ---- stage x-part (target prev + cond) BEFORE the spin: global-load
        // latency hides under the wait. As is free (prev iter's release barrier).
        if (j < Tx - 1) {
            u16x8 xv;
            if (j == 0) {
#pragma unroll
                for (int m = 0; m < 8; ++m) xv[m] = 0x3F80;  // bf16(1.0)
            } else {
                const float* tg = target + (gb_ * Tx + j) * OUTD + q_ * 8;
                const float4 t0 = *reinterpret_cast<const float4*>(tg);
                const float4 t1 = *reinterpret_cast<const float4*>(tg + 4);
                xv[0]=f2bf(t0.x); xv[1]=f2bf(t0.y); xv[2]=f2bf(t0.z); xv[3]=f2bf(t0.w);
                xv[4]=f2bf(t1.x); xv[5]=f2bf(t1.y); xv[6]=f2bf(t1.z); xv[7]=f2bf(t1.w);
            }
            *reinterpret_cast<u16x8*>(As + r_ * KP + q_ * 8)      = xv;
            *reinterpret_cast<u16x4*>(As + r_ * KP + 64 + q_ * 4) = cond_bf;
        }

        // ---- wait for h_{j-1} from all 64 group blocks
        if (j > 0 && tid == 0) {
            const u32* dp = done + (j - 1) * 8 + bs;
            while (__hip_atomic_load(dp, __ATOMIC_RELAXED, __HIP_MEMORY_SCOPE_AGENT) < 64u) {}
            __builtin_amdgcn_fence(__ATOMIC_ACQUIRE, "agent");  // inv L1/L2
        }
        __syncthreads();   // all waves ordered after the acquire

        // ---- stage h_{j-1} -> As cols 96..607 (one row per gl_lds16)
        {
            const u16* hp = (j & 1) ? hbuf1 : hbuf0;
#pragma unroll
            for (int it = 0; it < 8; ++it) {
                const int rr = w + it * 4;
                gl_lds16(hp + (bs * ROWS + rr) * HIDN + lane * 8,
                         (void*)(As + rr * KP + 96));
            }
        }
        __syncthreads();   // drains vmcnt: staging complete

        // ---- output projection out[:, j, hs] from the LDS h copy (j>=1)
        if (j >= 1) {
            const u16*   hrow = As + r_ * KP + 96 + q_ * 64;
            const float* wo   = Wo + q_ * 64;
            float p = 0.f;
#pragma unroll
            for (int i = 0; i < 8; ++i) {
                const int ii = (i + q_) & 7;   // rotate to break 8-way LDS bank conflict
                u16x8 hv  = *reinterpret_cast<const u16x8*>(hrow + ii * 8);
                float4 w0 = *reinterpret_cast<const float4*>(wo + ii * 8);
                float4 w1 = *reinterpret_cast<const float4*>(wo + ii * 8 + 4);
                p += bf2f(hv[0])*w0.x + bf2f(hv[1])*w0.y + bf2f(hv[2])*w0.z + bf2f(hv[3])*w0.w
                   + bf2f(hv[4])*w1.x + bf2f(hv[5])*w1.y + bf2f(hv[6])*w1.z + bf2f(hv[7])*w1.w;
            }
            p += __shfl_xor(p, 1); p += __shfl_xor(p, 2); p += __shfl_xor(p, 4);
            if (q_ == 0) out[gb_ * (Tx * OUTD) + j * OUTD + hs] = p + bo;
        }
        if (j == Tx - 1) break;               // final step: projection only

        // ---- gate GEMM: 4 waves x 16x16 tile, K = 19 chunks of 32
        f32x4 acc = {0.f, 0.f, 0.f, 0.f};
#pragma unroll
        for (int ck = 0; ck < 19; ++ck) {
            s16x8 a = *reinterpret_cast<const s16x8*>(ap + ck * 32);
            s16x8 b = *reinterpret_cast<const s16x8*>(bp + ck * 32);
            acc = __builtin_amdgcn_mfma_f32_16x16x32_bf16(a, b, acc, 0, 0, 0);
        }
        __syncthreads();                      // projection + MFMA reads done
#pragma unroll
        for (int t = 0; t < 4; ++t) gbuf[(row0 + t) * 36 + ncol] = acc[t];
        __syncthreads();

        // ---- cell update (c in register), write h_j
        {
            const float gi = gbuf[r_ * 36 +      q_] + bsum0;
            const float gf = gbuf[r_ * 36 +  8 + q_] + bsum1;
            const float gg = gbuf[r_ * 36 + 16 + q_] + bsum2;
            const float go = gbuf[r_ * 36 + 24 + q_] + bsum3;
            const float ig = sigmoidf_(gi), fg = sigmoidf_(gf);
            const float gt = tanhf(gg),     og = sigmoidf_(go);
            c_reg = fg * c_reg + ig * gt;
            u16* hn = (j & 1) ? hbuf0 : hbuf1;
            hn[gb_ * HIDN + hu_] = f2bf(og * tanhf(c_reg));
        }
        // release: each wave drains its stores + wbL2, then one flag add
        __builtin_amdgcn_fence(__ATOMIC_RELEASE, "agent");
        __syncthreads();
        if (tid == 0)
            __hip_atomic_fetch_add(done + j * 8 + bs, 1u,
                                   __ATOMIC_RELAXED, __HIP_MEMORY_SCOPE_AGENT);
    }
}

// ---------------------------------------------------------------------------
// fallback per-step kernel (previous verified path, used only if cooperative
// launch is rejected)
// ---------------------------------------------------------------------------
__global__ __launch_bounds__(256, 2) void step_kernel(
    int j,
    const float* __restrict__ target, const float* __restrict__ cond,
    const u16* __restrict__ hprev,    u16* __restrict__ hnext,
    float* __restrict__ cbuf,         const u16* __restrict__ Wg,
    const float* __restrict__ bsum,
    const float* __restrict__ W_out,  const float* __restrict__ b_out,
    float* __restrict__ out)
{
    const int tid  = threadIdx.x;
    const int bs   = blockIdx.x >> 6;
    const int hs   = blockIdx.x & 63;
    const int w    = tid >> 6;
    const int lane = tid & 63;

    if (j >= 1) {
        const int r = tid >> 3, q = tid & 7;
        const int gb = bs * ROWS + r;
        const u16*   hp = hprev + gb * HIDN + q * 64;
        const float* wo = W_out + hs * HIDN + q * 64;
        float p = 0.f;
#pragma unroll
        for (int i = 0; i < 8; ++i) {
            u16x8 hv = *reinterpret_cast<const u16x8*>(hp + i * 8);
            float4 w0 = *reinterpret_cast<const float4*>(wo + i * 8);
            float4 w1 = *reinterpret_cast<const float4*>(wo + i * 8 + 4);
            p += bf2f(hv[0]) * w0.x + bf2f(hv[1]) * w0.y + bf2f(hv[2]) * w0.z + bf2f(hv[3]) * w0.w
               + bf2f(hv[4]) * w1.x + bf2f(hv[5]) * w1.y + bf2f(hv[6]) * w1.z + bf2f(hv[7]) * w1.w;
        }
        p += __shfl_xor(p, 1); p += __shfl_xor(p, 2); p += __shfl_xor(p, 4);
        if (q == 0) out[gb * (Tx * OUTD) + j * OUTD + hs] = p + b_out[hs];
    }
    if (j >= Tx - 1) return;

    __shared__ __align__(16) char smem[2 * ROWS * KP * 2 + 1536];
    u16*   As   = (u16*)smem;
    u16*   Ws   = (u16*)(smem + ROWS * KP * 2);
    float* gbuf = (float*)smem;

    {
        const int r = tid >> 3, t8 = tid & 7;
        const int gb = bs * ROWS + r;
        const float* tg = target + (gb * Tx + j) * OUTD;
#pragma unroll
        for (int m = 0; m < 12; ++m) {
            const int k = t8 * 12 + m;
            float v;
            if (k < OUTD) v = (j == 0) ? 1.0f : tg[k];
            else          v = cond[gb * CND + (k - OUTD)];
            As[r * KP + k] = f2bf(v);
        }
    }
#pragma unroll
    for (int it = 0; it < 8; ++it) {
        const int rr = w + it * 4;
        gl_lds16(hprev + (bs * ROWS + rr) * HIDN + lane * 8, (void*)(As + rr * KP + 96));
    }
    {
        const u16* wsrc = Wg + hs * (NCOLS * KP);
#pragma unroll
        for (int it = 0; it < 10; ++it) {
            const int seg = it * 256 + w * 64;
            gl_lds16(wsrc + seg * 8 + lane * 8, (void*)(Ws + seg * 8));
        }
    }
    __syncthreads();

    const int mrow = ((w & 1) << 4) + (lane & 15);
    const int ncol = ((w >> 1) << 4) + (lane & 15);
    const int kq   = (lane >> 4) << 3;
    const u16* ap = As + mrow * KP + kq;
    const u16* bp = Ws + ncol * KP + kq;
    f32x4 acc = {0.f, 0.f, 0.f, 0.f};
#pragma unroll
    for (int ck = 0; ck < 19; ++ck) {
        s16x8 a = *reinterpret_cast<const s16x8*>(ap + ck * 32);
        s16x8 b = *reinterpret_cast<const s16x8*>(bp + ck * 32);
        acc = __builtin_amdgcn_mfma_f32_16x16x32_bf16(a, b, acc, 0, 0, 0);
    }
    __syncthreads();

    {
        const int row0 = ((w & 1) << 4) + ((lane >> 4) << 2);
#pragma unroll
        for (int t = 0; t < 4; ++t) gbuf[(row0 + t) * 36 + ncol] = acc[t];
    }
    __syncthreads();

    {
        const int r = tid >> 3, u = tid & 7;
        const int gb = bs * ROWS + r, hu = hs * 8 + u;
        const float gi = gbuf[r * 36 +      u] + bsum[0 * HIDN + hu];
        const float gf = gbuf[r * 36 +  8 + u] + bsum[1 * HIDN + hu];
        const float gg = gbuf[r * 36 + 16 + u] + bsum[2 * HIDN + hu];
        const float go = gbuf[r * 36 + 24 + u] + bsum[3 * HIDN + hu];
        const float ig = sigmoidf_(gi), fg = sigmoidf_(gf);
        const float gt = tanhf(gg),     og = sigmoidf_(go);
        const float co = cbuf[gb * HIDN + hu];
        const float cn = fg * co + ig * gt;
        cbuf[gb * HIDN + hu]  = cn;
        hnext[gb * HIDN + hu] = f2bf(og * tanhf(cn));
    }
}

// ---------------------------------------------------------------------------
extern "C" void kernel_launch(void* const* d_in, const int* in_sizes, int n_in,
                              void* d_out, int out_size, void* d_ws, size_t ws_size,
                              hipStream_t stream) {
    const float* latent = (const float*)d_in[0];
    const float* cond   = (const float*)d_in[1];
    const float* target = (const float*)d_in[2];
    const float* W_lh   = (const float*)d_in[3];
    const float* b_lh   = (const float*)d_in[4];
    const float* W_lc   = (const float*)d_in[5];
    const float* b_lc   = (const float*)d_in[6];
    const float* W_ih   = (const float*)d_in[7];
    const float* W_hh   = (const float*)d_in[8];
    const float* b_ih   = (const float*)d_in[9];
    const float* b_hh   = (const float*)d_in[10];
    const float* W_out  = (const float*)d_in[11];
    const float* b_out  = (const float*)d_in[12];

    float* out = (float*)d_out;
    char*  ws  = (char*)d_ws;
    u16*   Wg    = (u16*)(ws + WG_OFF);
    u16*   hbuf0 = (u16*)(ws + H0_OFF);
    u16*   hbuf1 = (u16*)(ws + H1_OFF);
    float* cbuf  = (float*)(ws + CB_OFF);
    float* bsum  = (float*)(ws + BS_OFF);
    u32*   done  = (u32*)(ws + DN_OFF);

    hipLaunchKernelGGL(prep_w, dim3(4864), dim3(256), 0, stream,
                       W_ih, W_hh, b_ih, b_hh, Wg, bsum, done);
    hipLaunchKernelGGL(init_kernel, dim3(Bx), dim3(256), 0, stream,
                       latent, W_lh, b_lh, W_lc, b_lc, hbuf0, cbuf, out);

    {
        const float* t_  = target;  const float* c_  = cond;
        u16*         h0_ = hbuf0;   u16*         h1_ = hbuf1;
        const float* cb_ = cbuf;    const u16*   wg_ = Wg;
        const float* bs_ = bsum;    const float* wo_ = W_out;
        const float* bo_ = b_out;   float*       o_  = out;
        u32*         dn_ = done;
        void* args[] = { &t_, &c_, &h0_, &h1_, &cb_, &wg_, &bs_, &wo_, &bo_, &o_, &dn_ };
        hipError_t err = hipLaunchCooperativeKernel(
            reinterpret_cast<const void*>(persist_kernel),
            dim3(512), dim3(256), args, 0, stream);
        if (err != hipSuccess) {
            // fallback: verified per-step launch loop
            for (int j = 0; j < Tx; ++j) {
                u16* hp = (j & 1) ? hbuf1 : hbuf0;
                u16* hn = (j & 1) ? hbuf0 : hbuf1;
                hipLaunchKernelGGL(step_kernel, dim3(512), dim3(256), 0, stream,
                                   j, target, cond, hp, hn, cbuf,
                                   Wg, bsum, W_out, b_out, out);
            }
        }
    }
}

// Round 2
// 2455.873 us; speedup vs baseline: 7.9227x; 7.9227x over previous
//
#include <hip/hip_runtime.h>

// Problem constants
#define Bx    256
#define Tx    512
#define LAT   128
#define CND   32
#define HIDN  512
#define OUTD  64
#define KD    608           // K = 64(prev) + 32(cond) + 512(h)
#define KP    616           // padded LDS/Wg stride in bf16 elems
#define ROWS  32            // batch rows per block
#define NCOLS 32            // gate cols per block (8 units x 4 gates)

typedef unsigned short u16;
typedef unsigned int   u32;
typedef short s16x8 __attribute__((ext_vector_type(8)));
typedef unsigned short u16x8 __attribute__((ext_vector_type(8)));
typedef unsigned short u16x4 __attribute__((ext_vector_type(4)));
typedef float f32x4 __attribute__((ext_vector_type(4)));

// ws layout (bytes)
#define WG_SLICE (NCOLS * KP * 2)            // 39424 B per hidden slice
#define WG_OFF   0
#define WG_BYTES (64 * WG_SLICE)             // 2523136
#define H0_OFF   (WG_BYTES)                  // h double-buffer, bf16 bits
#define H1_OFF   (H0_OFF + Bx * HIDN * 2)
#define CB_OFF   (H1_OFF + Bx * HIDN * 2)    // c0, fp32 (read once by persist)
#define BS_OFF   (CB_OFF + Bx * HIDN * 4)    // b_ih+b_hh, fp32 [2048]
#define DN_OFF   (BS_OFF + 4 * HIDN * 4)     // flags u32[8 groups][64 producers]

// persistent-kernel LDS layout
#define A_BYTES  (ROWS * KP * 2)             // 39424
#define SMEM_SZ  (2 * A_BYTES + HIDN * 4)    // 80896 -> 2 blocks/CU
#define WCHUNK   (A_BYTES / 16)              // 2464 16B chunks per W slice

__device__ __forceinline__ float sigmoidf_(float x) { return 1.0f / (1.0f + __expf(-x)); }

__device__ __forceinline__ u16 f2bf(float f) {          // RNE fp32 -> bf16 bits
    union { float f; u32 u; } v; v.f = f;
    u32 r = (v.u + 0x7FFFu + ((v.u >> 16) & 1u)) >> 16;
    return (u16)r;
}
__device__ __forceinline__ float bf2f(u16 s) {
    union { u32 u; float f; } v; v.u = ((u32)s) << 16;
    return v.f;
}
__device__ __forceinline__ void gl_lds16(const void* g, void* l) {
    __builtin_amdgcn_global_load_lds(
        (const __attribute__((address_space(1))) unsigned int*)g,
        (__attribute__((address_space(3))) unsigned int*)l, 16, 0, 0);
}
// agent-coherent (sc1) accessors: bypass non-coherent per-XCD L2, served at MALL
__device__ __forceinline__ u32 agent_ld(const u32* p) {
    return __hip_atomic_load(p, __ATOMIC_RELAXED, __HIP_MEMORY_SCOPE_AGENT);
}
__device__ __forceinline__ void agent_st(u32* p, u32 v) {
    __hip_atomic_store(p, v, __ATOMIC_RELAXED, __HIP_MEMORY_SCOPE_AGENT);
}

// ---------------------------------------------------------------------------
// prep: gather [W_ih | W_hh] -> bf16 Wg[hs][col=g*8+u][k(pad 616)]; bsum; flags=0
// ---------------------------------------------------------------------------
__global__ __launch_bounds__(256) void prep_w(
    const float* __restrict__ W_ih, const float* __restrict__ W_hh,
    const float* __restrict__ b_ih, const float* __restrict__ b_hh,
    u16* __restrict__ Wg, float* __restrict__ bsum, u32* __restrict__ done_arr)
{
    const int idx = blockIdx.x * 256 + threadIdx.x;
    if (idx < 64 * NCOLS * KD) {
        const int k   = idx % KD;
        const int t   = idx / KD;
        const int col = t % NCOLS;
        const int hs  = t / NCOLS;
        const int g = col >> 3, u = col & 7;
        const int n = g * HIDN + hs * 8 + u;
        const float v = (k < 96) ? W_ih[n * 96 + k] : W_hh[n * HIDN + (k - 96)];
        Wg[(hs * NCOLS + col) * KP + k] = f2bf(v);
    }
    if (idx < 4 * HIDN) bsum[idx] = b_ih[idx] + b_hh[idx];
    if (idx < 8 * 64)   done_arr[idx] = 0u;
}

// ---------------------------------------------------------------------------
// init: h0 (bf16) = latent @ W_lh^T + b_lh ; c0 (fp32) ; out[:,0,:] = 1
// ---------------------------------------------------------------------------
__global__ __launch_bounds__(256) void init_kernel(
    const float* __restrict__ latent, const float* __restrict__ W_lh,
    const float* __restrict__ b_lh,   const float* __restrict__ W_lc,
    const float* __restrict__ b_lc,   u16* __restrict__ h0,
    float* __restrict__ c0,           float* __restrict__ out)
{
    const int b = blockIdx.x;
    const float4* lat4 = reinterpret_cast<const float4*>(latent + b * LAT);
#pragma unroll
    for (int jj = 0; jj < 2; ++jj) {
        const int j = threadIdx.x + jj * 256;
        const float4* wh4 = reinterpret_cast<const float4*>(W_lh + j * LAT);
        const float4* wc4 = reinterpret_cast<const float4*>(W_lc + j * LAT);
        float sh = 0.f, sc = 0.f;
#pragma unroll 8
        for (int k = 0; k < LAT / 4; ++k) {
            float4 l = lat4[k], a = wh4[k], c = wc4[k];
            sh += l.x * a.x + l.y * a.y + l.z * a.z + l.w * a.w;
            sc += l.x * c.x + l.y * c.y + l.z * c.z + l.w * c.w;
        }
        h0[b * HIDN + j] = f2bf(sh + b_lh[j]);
        c0[b * HIDN + j] = sc + b_lc[j];
    }
    if (threadIdx.x < OUTD) out[b * (Tx * OUTD) + threadIdx.x] = 1.0f;
}

// ---------------------------------------------------------------------------
// persistent kernel: all 512 steps in one cooperative launch.
// Cross-block h goes through agent-scope (sc1) loads/stores -> coherent at MALL,
// NO L2 writeback/invalidate fences. Per-producer monotonic flags (value =
// #steps completed) polled lane-parallel by wave 0 -> no contended atomic RMW.
// ---------------------------------------------------------------------------
__global__ __launch_bounds__(256, 2) void persist_kernel(
    const float* __restrict__ target, const float* __restrict__ cond,
    u16* __restrict__ hbuf0, u16* __restrict__ hbuf1,
    const float* __restrict__ cbuf, const u16* __restrict__ Wg,
    const float* __restrict__ bsum, const float* __restrict__ W_out,
    const float* __restrict__ b_out, float* __restrict__ out,
    u32* __restrict__ done)
{
    const int tid  = threadIdx.x;
    const int bs   = blockIdx.x & 7;    // group = batch slice (XCD-local heuristic)
    const int hs   = blockIdx.x >> 3;   // hidden slice 0..63
    const int w    = tid >> 6;
    const int lane = tid & 63;

    __shared__ __align__(16) char smem[SMEM_SZ];
    u16*   As   = (u16*)smem;                   // [32][616] activations
    u16*   Ws   = (u16*)(smem + A_BYTES);       // [32][616] weights (persistent)
    float* Wo   = (float*)(smem + 2 * A_BYTES); // [512] W_out col (persistent)
    float* gbuf = (float*)smem;                 // [32][36] alias over As rows 0-3

    // ---- one-time: W slice -> LDS (2464 x 16B chunks)
    {
        const u16* wsrc = Wg + hs * (NCOLS * KP);
#pragma unroll
        for (int it = 0; it < 10; ++it) {
            const int base = it * 256 + w * 64;
            if (base + lane < WCHUNK)
                gl_lds16(wsrc + (base + lane) * 8, (void*)(Ws + base * 8));
        }
    }
    if (tid < 128)
        reinterpret_cast<float4*>(Wo)[tid] =
            reinterpret_cast<const float4*>(W_out + hs * HIDN)[tid];

    const int r_  = tid >> 3, q_ = tid & 7;     // (row, unit) ownership
    const int gb_ = bs * ROWS + r_;
    const int hu_ = hs * 8 + q_;
    float c_reg = cbuf[gb_ * HIDN + hu_];       // c lives in a register forever
    const float bsum0 = bsum[0 * HIDN + hu_];
    const float bsum1 = bsum[1 * HIDN + hu_];
    const float bsum2 = bsum[2 * HIDN + hu_];
    const float bsum3 = bsum[3 * HIDN + hu_];
    const float bo    = b_out[hs];

    u16x4 cond_bf;                              // cond cached in regs
    {
        const float4 cv = *reinterpret_cast<const float4*>(cond + gb_ * CND + q_ * 4);
        cond_bf[0] = f2bf(cv.x); cond_bf[1] = f2bf(cv.y);
        cond_bf[2] = f2bf(cv.z); cond_bf[3] = f2bf(cv.w);
    }

    // MFMA geometry
    const int mrow = ((w & 1) << 4) + (lane & 15);
    const int ncol = ((w >> 1) << 4) + (lane & 15);
    const int kq   = (lane >> 4) << 3;
    const u16* ap  = As + mrow * KP + kq;
    const u16* bp  = Ws + ncol * KP + kq;
    const int row0 = ((w & 1) << 4) + ((lane >> 4) << 2);

    for (int j = 0; j < Tx; ++j) {
        // ---- stage x-part (target prev + cond) before the wait
        if (j < Tx - 1) {
            u16x8 xv;
            if (j == 0) {
#pragma unroll
                for (int m = 0; m < 8; ++m) xv[m] = 0x3F80;  // bf16(1.0)
            } else {
                const float* tg = target + (gb_ * Tx + j) * OUTD + q_ * 8;
                const float4 t0 = *reinterpret_cast<const float4*>(tg);
                const float4 t1 = *reinterpret_cast<const float4*>(tg + 4);
                xv[0]=f2bf(t0.x); xv[1]=f2bf(t0.y); xv[2]=f2bf(t0.z); xv[3]=f2bf(t0.w);
                xv[4]=f2bf(t1.x); xv[5]=f2bf(t1.y); xv[6]=f2bf(t1.z); xv[7]=f2bf(t1.w);
            }
            *reinterpret_cast<u16x8*>(As + r_ * KP + q_ * 8)      = xv;
            *reinterpret_cast<u16x4*>(As + r_ * KP + 64 + q_ * 4) = cond_bf;
        }

        // ---- wave 0: lane-parallel wait for all 64 group producers at step j
        if (j > 0 && tid < 64) {
            const u32* fp = done + bs * 64 + tid;
            for (;;) {
                u32 v = agent_ld(fp);
                if (__all((int)(v >= (u32)j))) break;
            }
        }
        __syncthreads();

        // ---- stage h_{j-1} -> As cols 96..607 via agent (sc1) loads.
        // row i is wave-uniform per iteration; lanes hit 64 consecutive dwords
        // in LDS -> conflict-free.
        {
            const u16* hp = (j & 1) ? hbuf1 : hbuf0;
            const u32* hp32 = (const u32*)(hp + bs * ROWS * HIDN);
            u32 hv[32];
#pragma unroll
            for (int i = 0; i < 32; ++i)
                hv[i] = agent_ld(hp32 + i * 256 + tid);
#pragma unroll
            for (int i = 0; i < 32; ++i)
                *(((u32*)(As + i * KP + 96)) + tid) = hv[i];
        }
        __syncthreads();   // staging + (first iter) Ws/Wo complete

        // ---- output projection out[:, j, hs] from the LDS h copy (j>=1)
        if (j >= 1) {
            const u16*   hrow = As + r_ * KP + 96 + q_ * 64;
            const float* wo   = Wo + q_ * 64;
            float p = 0.f;
#pragma unroll
            for (int i = 0; i < 8; ++i) {
                const int ii = (i + q_) & 7;   // rotate to spread LDS banks
                u16x8 hv  = *reinterpret_cast<const u16x8*>(hrow + ii * 8);
                float4 w0 = *reinterpret_cast<const float4*>(wo + ii * 8);
                float4 w1 = *reinterpret_cast<const float4*>(wo + ii * 8 + 4);
                p += bf2f(hv[0])*w0.x + bf2f(hv[1])*w0.y + bf2f(hv[2])*w0.z + bf2f(hv[3])*w0.w
                   + bf2f(hv[4])*w1.x + bf2f(hv[5])*w1.y + bf2f(hv[6])*w1.z + bf2f(hv[7])*w1.w;
            }
            p += __shfl_xor(p, 1); p += __shfl_xor(p, 2); p += __shfl_xor(p, 4);
            if (q_ == 0) out[gb_ * (Tx * OUTD) + j * OUTD + hs] = p + bo;
        }
        if (j == Tx - 1) break;               // final step: projection only

        // ---- gate GEMM: 4 waves x 16x16 tile, K = 19 chunks of 32
        f32x4 acc = {0.f, 0.f, 0.f, 0.f};
#pragma unroll
        for (int ck = 0; ck < 19; ++ck) {
            s16x8 a = *reinterpret_cast<const s16x8*>(ap + ck * 32);
            s16x8 b = *reinterpret_cast<const s16x8*>(bp + ck * 32);
            acc = __builtin_amdgcn_mfma_f32_16x16x32_bf16(a, b, acc, 0, 0, 0);
        }
        __syncthreads();                      // projection + MFMA reads done
#pragma unroll
        for (int t = 0; t < 4; ++t) gbuf[(row0 + t) * 36 + ncol] = acc[t];
        __syncthreads();

        // ---- cell update (c in register), write h_j via agent (sc1) stores
        {
            const float gi = gbuf[r_ * 36 +      q_] + bsum0;
            const float gf = gbuf[r_ * 36 +  8 + q_] + bsum1;
            const float gg = gbuf[r_ * 36 + 16 + q_] + bsum2;
            const float go = gbuf[r_ * 36 + 24 + q_] + bsum3;
            const float ig = sigmoidf_(gi), fg = sigmoidf_(gf);
            const float gt = tanhf(gg),     og = sigmoidf_(go);
            c_reg = fg * c_reg + ig * gt;
            const u32 hb = (u32)f2bf(og * tanhf(c_reg));
            const u32 nb = (u32)__shfl_xor((int)hb, 1);   // partner q_^1
            if ((q_ & 1) == 0) {
                u16* hn = (j & 1) ? hbuf0 : hbuf1;
                agent_st(((u32*)(hn + gb_ * HIDN)) + (hu_ >> 1), hb | (nb << 16));
            }
        }
        // per-wave drain of sc1 stores, block barrier, then publish flag
        asm volatile("s_waitcnt vmcnt(0)" ::: "memory");
        __syncthreads();
        if (tid == 0)
            agent_st(done + bs * 64 + hs, (u32)(j + 1));
    }
}

// ---------------------------------------------------------------------------
// fallback per-step kernel (verified path, used only if cooperative launch
// is rejected)
// ---------------------------------------------------------------------------
__global__ __launch_bounds__(256, 2) void step_kernel(
    int j,
    const float* __restrict__ target, const float* __restrict__ cond,
    const u16* __restrict__ hprev,    u16* __restrict__ hnext,
    float* __restrict__ cbuf,         const u16* __restrict__ Wg,
    const float* __restrict__ bsum,
    const float* __restrict__ W_out,  const float* __restrict__ b_out,
    float* __restrict__ out)
{
    const int tid  = threadIdx.x;
    const int bs   = blockIdx.x >> 6;
    const int hs   = blockIdx.x & 63;
    const int w    = tid >> 6;
    const int lane = tid & 63;

    if (j >= 1) {
        const int r = tid >> 3, q = tid & 7;
        const int gb = bs * ROWS + r;
        const u16*   hp = hprev + gb * HIDN + q * 64;
        const float* wo = W_out + hs * HIDN + q * 64;
        float p = 0.f;
#pragma unroll
        for (int i = 0; i < 8; ++i) {
            u16x8 hv = *reinterpret_cast<const u16x8*>(hp + i * 8);
            float4 w0 = *reinterpret_cast<const float4*>(wo + i * 8);
            float4 w1 = *reinterpret_cast<const float4*>(wo + i * 8 + 4);
            p += bf2f(hv[0]) * w0.x + bf2f(hv[1]) * w0.y + bf2f(hv[2]) * w0.z + bf2f(hv[3]) * w0.w
               + bf2f(hv[4]) * w1.x + bf2f(hv[5]) * w1.y + bf2f(hv[6]) * w1.z + bf2f(hv[7]) * w1.w;
        }
        p += __shfl_xor(p, 1); p += __shfl_xor(p, 2); p += __shfl_xor(p, 4);
        if (q == 0) out[gb * (Tx * OUTD) + j * OUTD + hs] = p + b_out[hs];
    }
    if (j >= Tx - 1) return;

    __shared__ __align__(16) char smem[2 * ROWS * KP * 2 + 1536];
    u16*   As   = (u16*)smem;
    u16*   Ws   = (u16*)(smem + ROWS * KP * 2);
    float* gbuf = (float*)smem;

    {
        const int r = tid >> 3, t8 = tid & 7;
        const int gb = bs * ROWS + r;
        const float* tg = target + (gb * Tx + j) * OUTD;
#pragma unroll
        for (int m = 0; m < 12; ++m) {
            const int k = t8 * 12 + m;
            float v;
            if (k < OUTD) v = (j == 0) ? 1.0f : tg[k];
            else          v = cond[gb * CND + (k - OUTD)];
            As[r * KP + k] = f2bf(v);
        }
    }
#pragma unroll
    for (int it = 0; it < 8; ++it) {
        const int rr = w + it * 4;
        gl_lds16(hprev + (bs * ROWS + rr) * HIDN + lane * 8, (void*)(As + rr * KP + 96));
    }
    {
        const u16* wsrc = Wg + hs * (NCOLS * KP);
#pragma unroll
        for (int it = 0; it < 10; ++it) {
            const int seg = it * 256 + w * 64;
            gl_lds16(wsrc + seg * 8 + lane * 8, (void*)(Ws + seg * 8));
        }
    }
    __syncthreads();

    const int mrow = ((w & 1) << 4) + (lane & 15);
    const int ncol = ((w >> 1) << 4) + (lane & 15);
    const int kq   = (lane >> 4) << 3;
    const u16* ap = As + mrow * KP + kq;
    const u16* bp = Ws + ncol * KP + kq;
    f32x4 acc = {0.f, 0.f, 0.f, 0.f};
#pragma unroll
    for (int ck = 0; ck < 19; ++ck) {
        s16x8 a = *reinterpret_cast<const s16x8*>(ap + ck * 32);
        s16x8 b = *reinterpret_cast<const s16x8*>(bp + ck * 32);
        acc = __builtin_amdgcn_mfma_f32_16x16x32_bf16(a, b, acc, 0, 0, 0);
    }
    __syncthreads();

    {
        const int row0 = ((w & 1) << 4) + ((lane >> 4) << 2);
#pragma unroll
        for (int t = 0; t < 4; ++t) gbuf[(row0 + t) * 36 + ncol] = acc[t];
    }
    __syncthreads();

    {
        const int r = tid >> 3, u = tid & 7;
        const int gb = bs * ROWS + r, hu = hs * 8 + u;
        const float gi = gbuf[r * 36 +      u] + bsum[0 * HIDN + hu];
        const float gf = gbuf[r * 36 +  8 + u] + bsum[1 * HIDN + hu];
        const float gg = gbuf[r * 36 + 16 + u] + bsum[2 * HIDN + hu];
        const float go = gbuf[r * 36 + 24 + u] + bsum[3 * HIDN + hu];
        const float ig = sigmoidf_(gi), fg = sigmoidf_(gf);
        const float gt = tanhf(gg),     og = sigmoidf_(go);
        const float co = cbuf[gb * HIDN + hu];
        const float cn = fg * co + ig * gt;
        cbuf[gb * HIDN + hu]  = cn;
        hnext[gb * HIDN + hu] = f2bf(og * tanhf(cn));
    }
}

// ---------------------------------------------------------------------------
extern "C" void kernel_launch(void* const* d_in, const int* in_sizes, int n_in,
                              void* d_out, int out_size, void* d_ws, size_t ws_size,
                              hipStream_t stream) {
    const float* latent = (const float*)d_in[0];
    const float* cond   = (const float*)d_in[1];
    const float* target = (const float*)d_in[2];
    const float* W_lh   = (const float*)d_in[3];
    const float* b_lh   = (const float*)d_in[4];
    const float* W_lc   = (const float*)d_in[5];
    const float* b_lc   = (const float*)d_in[6];
    const float* W_ih   = (const float*)d_in[7];
    const float* W_hh   = (const float*)d_in[8];
    const float* b_ih   = (const float*)d_in[9];
    const float* b_hh   = (const float*)d_in[10];
    const float* W_out  = (const float*)d_in[11];
    const float* b_out  = (const float*)d_in[12];

    float* out = (float*)d_out;
    char*  ws  = (char*)d_ws;
    u16*   Wg    = (u16*)(ws + WG_OFF);
    u16*   hbuf0 = (u16*)(ws + H0_OFF);
    u16*   hbuf1 = (u16*)(ws + H1_OFF);
    float* cbuf  = (float*)(ws + CB_OFF);
    float* bsum  = (float*)(ws + BS_OFF);
    u32*   done  = (u32*)(ws + DN_OFF);

    hipLaunchKernelGGL(prep_w, dim3(4864), dim3(256), 0, stream,
                       W_ih, W_hh, b_ih, b_hh, Wg, bsum, done);
    hipLaunchKernelGGL(init_kernel, dim3(Bx), dim3(256), 0, stream,
                       latent, W_lh, b_lh, W_lc, b_lc, hbuf0, cbuf, out);

    {
        const float* t_  = target;  const float* c_  = cond;
        u16*         h0_ = hbuf0;   u16*         h1_ = hbuf1;
        const float* cb_ = cbuf;    const u16*   wg_ = Wg;
        const float* bs_ = bsum;    const float* wo_ = W_out;
        const float* bo_ = b_out;   float*       o_  = out;
        u32*         dn_ = done;
        void* args[] = { &t_, &c_, &h0_, &h1_, &cb_, &wg_, &bs_, &wo_, &bo_, &o_, &dn_ };
        hipError_t err = hipLaunchCooperativeKernel(
            reinterpret_cast<const void*>(persist_kernel),
            dim3(512), dim3(256), args, 0, stream);
        if (err != hipSuccess) {
            // fallback: verified per-step launch loop
            for (int j = 0; j < Tx; ++j) {
                u16* hp = (j & 1) ? hbuf1 : hbuf0;
                u16* hn = (j & 1) ? hbuf0 : hbuf1;
                hipLaunchKernelGGL(step_kernel, dim3(512), dim3(256), 0, stream,
                                   j, target, cond, hp, hn, cbuf,
                                   Wg, bsum, W_out, b_out, out);
            }
        }
    }
}